// Round 1
// baseline (272.566 us; speedup 1.0000x reference)
//
#include <hip/hip_runtime.h>

typedef unsigned short u16;
typedef unsigned int u32;
typedef __attribute__((ext_vector_type(4))) float vfloat4;
typedef __attribute__((ext_vector_type(8))) short vshort8;
typedef __attribute__((ext_vector_type(4))) short vshort4;

#define DEV __device__ __forceinline__

DEV u16 f2b(float f){
  u32 u = __builtin_bit_cast(u32, f);
  u = (u + 0x7fffu + ((u >> 16) & 1u)) >> 16;
  return (u16)u;
}

// ---------------- K1: per-(b,c) sum & sumsq over N=1024 ----------------
__global__ void k_stats(const float* __restrict__ x, float* __restrict__ osum, float* __restrict__ osq){
  int row = blockIdx.x;                       // b*256 + c
  const vfloat4* xr = (const vfloat4*)(x + (size_t)row * 1024);
  vfloat4 v = xr[threadIdx.x];
  float s = v[0]+v[1]+v[2]+v[3];
  float q = v[0]*v[0]+v[1]*v[1]+v[2]*v[2]+v[3]*v[3];
  #pragma unroll
  for (int m = 1; m < 64; m <<= 1){ s += __shfl_xor(s, m); q += __shfl_xor(q, m); }
  __shared__ float ls[4], lq[4];
  int w = threadIdx.x >> 6;
  if ((threadIdx.x & 63) == 0){ ls[w] = s; lq[w] = q; }
  __syncthreads();
  if (threadIdx.x == 0){
    osum[row] = ls[0]+ls[1]+ls[2]+ls[3];
    osq[row]  = lq[0]+lq[1]+lq[2]+lq[3];
  }
}

// ---------------- K2: per-batch GN affine + SE gate ----------------
__global__ void k_prep(const float* __restrict__ sum, const float* __restrict__ sq,
                       const float* __restrict__ gamma, const float* __restrict__ beta,
                       const float* __restrict__ w_se1, const float* __restrict__ b_se1,
                       const float* __restrict__ w_se2, const float* __restrict__ b_se2,
                       float* __restrict__ a_scale, float* __restrict__ bsh, float* __restrict__ gate){
  int b = blockIdx.x, c = threadIdx.x;        // 256 threads
  __shared__ float ssh[256], qsh[256], pooled[256], h1[64], meang[32], rstdg[32];
  float s = sum[b*256 + c], q = sq[b*256 + c];
  ssh[c] = s; qsh[c] = q; pooled[c] = s * (1.f/1024.f);
  __syncthreads();
  if (c < 32){
    float gs = 0.f, gq = 0.f;
    #pragma unroll
    for (int i = 0; i < 8; i++){ gs += ssh[c*8+i]; gq += qsh[c*8+i]; }
    float mean = gs * (1.f/8192.f);
    float var  = gq * (1.f/8192.f) - mean*mean;
    meang[c] = mean; rstdg[c] = rsqrtf(var + 1e-5f);
  }
  __syncthreads();
  float rs = rstdg[c>>3], mn = meang[c>>3], g = gamma[c];
  a_scale[b*256+c] = rs*g;
  bsh[b*256+c]     = beta[c] - mn*rs*g;
  if (c < 64){
    float acc = b_se1[c];
    const float* wr = w_se1 + c*256;
    for (int i = 0; i < 256; i++) acc += pooled[i]*wr[i];
    h1[c] = fmaxf(acc, 0.f);
  }
  __syncthreads();
  float acc = b_se2[c];
  const float* wr2 = w_se2 + c*64;
  #pragma unroll
  for (int j = 0; j < 64; j++) acc += h1[j]*wr2[j];
  gate[b*256+c] = 1.f / (1.f + __expf(-acc));
}

// ---------------- K3w: weights -> bf16 ----------------
__global__ void k_wcvt(const float* __restrict__ wq, const float* __restrict__ wp,
                       u16* __restrict__ wqb, u16* __restrict__ wpb){
  int i = blockIdx.x*256 + threadIdx.x;       // 1024 blocks -> 262144 threads
  if (i < 196608) wqb[i] = f2b(wq[i]);
  else            wpb[i-196608] = f2b(wp[i-196608]);
}

// ---------------- K3: xs_t[b,n,c] = bf16(a*x + bsh), transposed ----------------
__global__ void k_xt(const float* __restrict__ x, const float* __restrict__ a_s,
                     const float* __restrict__ bsh, u16* __restrict__ xs_t){
  __shared__ float t[64][65];
  int b = blockIdx.z, c0 = blockIdx.y*64, n0 = blockIdx.x*64;
  int tid = threadIdx.x;
  int rr = tid >> 4, cc = (tid & 15)*4;
  #pragma unroll
  for (int itr = 0; itr < 4; itr++){
    int r = rr + itr*16;
    int c = c0 + r;
    float a = a_s[b*256 + c], bs = bsh[b*256 + c];
    vfloat4 v = *(const vfloat4*)(x + ((size_t)(b*256 + c))*1024 + n0 + cc);
    t[r][cc]   = v[0]*a + bs;
    t[r][cc+1] = v[1]*a + bs;
    t[r][cc+2] = v[2]*a + bs;
    t[r][cc+3] = v[3]*a + bs;
  }
  __syncthreads();
  int cl = tid & 63, rg = tid >> 6;
  #pragma unroll
  for (int it2 = 0; it2 < 16; it2++){
    int nl = rg*16 + it2;
    xs_t[((size_t)b*1024 + n0 + nl)*256 + c0 + cl] = f2b(t[cl][nl]);
  }
}

// ---------------- K4: qkv GEMM (bf16 MFMA), store qT,kT,[c][n] v ----------------
// A = w_qkv [768][256], B = xs_t[n][c] (both K-contiguous). D[o][n].
__global__ __launch_bounds__(256) void k_qkv(
    const u16* __restrict__ wq_b, const u16* __restrict__ xs_t,
    const float* __restrict__ b_qkv,
    u16* __restrict__ qt, u16* __restrict__ ktw, u16* __restrict__ vv){
  __shared__ u16 Alds[128*40];   // rows 32c + 8-short pad (80B): 2-way banks = free
  __shared__ u16 Blds[128*40];
  int b  = blockIdx.z;
  int o0 = blockIdx.y * 128;
  int n0 = blockIdx.x * 128;
  int tid = threadIdx.x;
  int w = tid >> 6, lane = tid & 63, lo = lane & 15, hi = lane >> 4;
  int wr = w >> 1, wc = w & 1;
  vfloat4 acc[4][4];
  #pragma unroll
  for (int i = 0; i < 4; i++)
    #pragma unroll
    for (int j = 0; j < 4; j++) acc[i][j] = vfloat4{0.f,0.f,0.f,0.f};

  for (int ks = 0; ks < 8; ks++){
    int c0 = ks*32;
    __syncthreads();
    #pragma unroll
    for (int i = 0; i < 2; i++){
      int cid = tid + i*256;
      int row = cid >> 2, h4 = cid & 3;
      vshort8 a = *(const vshort8*)(wq_b + (o0+row)*256 + c0 + h4*8);
      *(vshort8*)(Alds + row*40 + h4*8) = a;
      vshort8 bl = *(const vshort8*)(xs_t + ((size_t)b*1024 + n0 + row)*256 + c0 + h4*8);
      *(vshort8*)(Blds + row*40 + h4*8) = bl;
    }
    __syncthreads();
    vshort8 af[4], bf[4];
    #pragma unroll
    for (int of = 0; of < 4; of++) af[of] = *(const vshort8*)(Alds + (wr*64+of*16+lo)*40 + hi*8);
    #pragma unroll
    for (int nf = 0; nf < 4; nf++) bf[nf] = *(const vshort8*)(Blds + (wc*64+nf*16+lo)*40 + hi*8);
    #pragma unroll
    for (int of = 0; of < 4; of++)
      #pragma unroll
      for (int nf = 0; nf < 4; nf++)
        acc[of][nf] = __builtin_amdgcn_mfma_f32_16x16x32_bf16(af[of], bf[nf], acc[of][nf], 0, 0, 0);
  }

  int kind = blockIdx.y >> 1;   // 0=q, 1=k, 2=v (o-tiles of 128 within 256-blocks)
  #pragma unroll
  for (int of = 0; of < 4; of++){
    int ob = o0 + wr*64 + of*16 + hi*4;       // 4 contiguous o per lane (reg dim)
    vfloat4 bq = *(const vfloat4*)(b_qkv + ob);
    #pragma unroll
    for (int nf = 0; nf < 4; nf++){
      int n = n0 + wc*64 + nf*16 + lo;
      vfloat4 val = acc[of][nf];
      #pragma unroll
      for (int r = 0; r < 4; r++) val[r] += bq[r];
      if (kind == 0){
        vshort4 p;
        #pragma unroll
        for (int r = 0; r < 4; r++) p[r] = (short)f2b(val[r] * 0.0625f);  // fold 1/sqrt(C)
        *(vshort4*)(qt + ((size_t)b*1024 + n)*256 + ob) = p;
      } else if (kind == 1){
        vshort4 p;
        #pragma unroll
        for (int r = 0; r < 4; r++) p[r] = (short)f2b(val[r]);
        *(vshort4*)(ktw + ((size_t)b*1024 + n)*256 + (ob - 256)) = p;
      } else {
        #pragma unroll
        for (int r = 0; r < 4; r++)
          vv[((size_t)b*256 + (ob - 512 + r))*1024 + n] = f2b(val[r]);
      }
    }
  }
}

// ---------------- K5: flash attention + proj + SE gate + residual ----------------
__global__ __launch_bounds__(256) void k_attn(
    const u16* __restrict__ qt, const u16* __restrict__ ktw, const u16* __restrict__ vv,
    const u16* __restrict__ wp_b, const float* __restrict__ b_proj,
    const float* __restrict__ gate, const float* __restrict__ x,
    float* __restrict__ out){
  __shared__ u16 smem[18688];                // 36.5 KB
  u16* Kt = smem;                             // [32][264]  (512B rows + 16B pad)
  u16* Vl = smem + 8448;                      // [256][40]  (64B rows + 16B pad)
  u16* Ol = smem;                             // [64][264]  overlay after loop
  int it = blockIdx.x, b = blockIdx.y;
  int tid = threadIdx.x, w = tid >> 6, lane = tid & 63, lo = lane & 15, hi = lane >> 4;
  int i0 = it*64;
  int iw = i0 + w*16 + lo;                    // this lane's query row

  vshort8 qf[8];
  #pragma unroll
  for (int ct = 0; ct < 8; ct++)
    qf[ct] = *(const vshort8*)(qt + ((size_t)b*1024 + iw)*256 + ct*32 + hi*8);

  vfloat4 Oacc[16];
  #pragma unroll
  for (int i = 0; i < 16; i++) Oacc[i] = vfloat4{0.f,0.f,0.f,0.f};
  float m_run = -1e30f, l_run = 0.f;

  for (int jt = 0; jt < 1024; jt += 32){
    __syncthreads();
    #pragma unroll
    for (int i = 0; i < 4; i++){               // stage K tile [32 j][256 c]
      int cid = tid + i*256;
      int row = cid >> 5, ch = cid & 31;
      vshort8 kv = *(const vshort8*)(ktw + ((size_t)b*1024 + jt + row)*256 + ch*8);
      *(vshort8*)(Kt + row*264 + ch*8) = kv;
    }
    #pragma unroll
    for (int i = 0; i < 4; i++){               // stage V tile [256 c][32 j]
      int cid = tid + i*256;
      int row = cid >> 2, h4 = cid & 3;
      vshort8 vw = *(const vshort8*)(vv + ((size_t)b*256 + row)*1024 + jt + h4*8);
      *(vshort8*)(Vl + row*40 + h4*8) = vw;
    }
    __syncthreads();

    // S^T = K · Q : D[j][i], col=i=lo, row=j=hi*4+reg (+16 for st1)
    vfloat4 st0 = vfloat4{0.f,0.f,0.f,0.f}, st1 = vfloat4{0.f,0.f,0.f,0.f};
    #pragma unroll
    for (int ct = 0; ct < 8; ct++){
      vshort8 k0 = *(const vshort8*)(Kt + lo*264      + ct*32 + hi*8);
      vshort8 k1 = *(const vshort8*)(Kt + (16+lo)*264 + ct*32 + hi*8);
      st0 = __builtin_amdgcn_mfma_f32_16x16x32_bf16(k0, qf[ct], st0, 0,0,0);
      st1 = __builtin_amdgcn_mfma_f32_16x16x32_bf16(k1, qf[ct], st1, 0,0,0);
    }

    // online softmax (stats per query row i=lo, replicated over hi lanes)
    float pm = fmaxf(fmaxf(fmaxf(st0[0], st0[1]), fmaxf(st0[2], st0[3])),
                     fmaxf(fmaxf(st1[0], st1[1]), fmaxf(st1[2], st1[3])));
    pm = fmaxf(pm, __shfl_xor(pm, 16));
    pm = fmaxf(pm, __shfl_xor(pm, 32));
    float mnew = fmaxf(m_run, pm);
    float corr = __expf(m_run - mnew);
    float p0[4], p1[4], ps = 0.f;
    #pragma unroll
    for (int e = 0; e < 4; e++){
      p0[e] = __expf(st0[e] - mnew);
      p1[e] = __expf(st1[e] - mnew);
      ps += p0[e] + p1[e];
    }
    ps += __shfl_xor(ps, 16); ps += __shfl_xor(ps, 32);
    l_run = l_run*corr + ps; m_run = mnew;

    vshort8 pf;                                // B-frag: k=j, pi(hi,e): e<4 -> hi*4+e ; e>=4 -> 16+hi*4+(e-4)
    #pragma unroll
    for (int e = 0; e < 4; e++){ pf[e] = (short)f2b(p0[e]); pf[e+4] = (short)f2b(p1[e]); }
    #pragma unroll
    for (int i = 0; i < 16; i++) Oacc[i] *= corr;

    // O[c][i] += V · P  (A=V with same pi -> two ds_read_b64 per frag)
    #pragma unroll
    for (int ct2 = 0; ct2 < 16; ct2++){
      int c = ct2*16 + lo;
      vshort4 v0 = *(const vshort4*)(Vl + c*40 + hi*4);
      vshort4 v1 = *(const vshort4*)(Vl + c*40 + 16 + hi*4);
      vshort8 vf = __builtin_shufflevector(v0, v1, 0,1,2,3,4,5,6,7);
      Oacc[ct2] = __builtin_amdgcn_mfma_f32_16x16x32_bf16(vf, pf, Oacc[ct2], 0,0,0);
    }
  }

  float inv = 1.f / l_run;
  __syncthreads();
  #pragma unroll
  for (int ct2 = 0; ct2 < 16; ct2++){          // O -> LDS [i][c] bf16
    vshort4 p;
    #pragma unroll
    for (int r = 0; r < 4; r++) p[r] = (short)f2b(Oacc[ct2][r]*inv);
    *(vshort4*)(Ol + (w*16+lo)*264 + ct2*16 + hi*4) = p;
  }
  __syncthreads();

  // proj: wave w does o in [w*64, w*64+64) x all 64 i
  vfloat4 acc2[4][4];
  #pragma unroll
  for (int i = 0; i < 4; i++)
    #pragma unroll
    for (int j = 0; j < 4; j++) acc2[i][j] = vfloat4{0.f,0.f,0.f,0.f};
  #pragma unroll
  for (int ct = 0; ct < 8; ct++){
    vshort8 wf[4], ofr[4];
    #pragma unroll
    for (int o4 = 0; o4 < 4; o4++)
      wf[o4] = *(const vshort8*)(wp_b + (w*64+o4*16+lo)*256 + ct*32 + hi*8);
    #pragma unroll
    for (int i4 = 0; i4 < 4; i4++)
      ofr[i4] = *(const vshort8*)(Ol + (i4*16+lo)*264 + ct*32 + hi*8);
    #pragma unroll
    for (int o4 = 0; o4 < 4; o4++)
      #pragma unroll
      for (int i4 = 0; i4 < 4; i4++)
        acc2[o4][i4] = __builtin_amdgcn_mfma_f32_16x16x32_bf16(wf[o4], ofr[i4], acc2[o4][i4], 0,0,0);
  }

  #pragma unroll
  for (int o4 = 0; o4 < 4; o4++){
    int ob = w*64 + o4*16 + hi*4;
    vfloat4 bp = *(const vfloat4*)(b_proj + ob);
    vfloat4 gt = *(const vfloat4*)(gate + b*256 + ob);
    #pragma unroll
    for (int i4 = 0; i4 < 4; i4++){
      int n = i0 + i4*16 + lo;
      #pragma unroll
      for (int r = 0; r < 4; r++){
        size_t idx = ((size_t)(b*256) + ob + r)*1024 + n;
        out[idx] = x[idx] + (acc2[o4][i4][r] + bp[r]) * gt[r];
      }
    }
  }
}

// ---------------- launch ----------------
extern "C" void kernel_launch(void* const* d_in, const int* in_sizes, int n_in,
                              void* d_out, int out_size, void* d_ws, size_t ws_size,
                              hipStream_t stream){
  const float* x      = (const float*)d_in[0];
  const float* gamma  = (const float*)d_in[1];
  const float* beta   = (const float*)d_in[2];
  const float* w_qkv  = (const float*)d_in[3];
  const float* b_qkv  = (const float*)d_in[4];
  const float* w_proj = (const float*)d_in[5];
  const float* b_proj = (const float*)d_in[6];
  const float* w_se1  = (const float*)d_in[7];
  const float* b_se1  = (const float*)d_in[8];
  const float* w_se2  = (const float*)d_in[9];
  const float* b_se2  = (const float*)d_in[10];
  float* out = (float*)d_out;
  char* ws = (char*)d_ws;

  float* sum  = (float*)(ws + 0);          // 32 KB
  float* sq   = (float*)(ws + 32768);      // 32 KB
  float* a_s  = (float*)(ws + 65536);      // 32 KB
  float* bsh  = (float*)(ws + 98304);      // 32 KB
  float* gate = (float*)(ws + 131072);     // 32 KB
  u16* wq_b   = (u16*)(ws + 163840);       // 384 KB
  u16* wp_b   = (u16*)(ws + 557056);       // 128 KB
  u16* xs_t   = (u16*)(ws + 688128);       // 16 MB  [B,N,C] bf16
  u16* qt     = (u16*)(ws + 17465344);     // 16 MB  [B,N,C] bf16 (scale folded)
  u16* ktw    = (u16*)(ws + 34242560);     // 16 MB  [B,N,C] bf16
  u16* vv     = (u16*)(ws + 51019776);     // 16 MB  [B,C,N] bf16

  k_stats<<<8192, 256, 0, stream>>>(x, sum, sq);
  k_wcvt <<<1024, 256, 0, stream>>>(w_qkv, w_proj, wq_b, wp_b);
  k_prep <<<32,   256, 0, stream>>>(sum, sq, gamma, beta, w_se1, b_se1, w_se2, b_se2, a_s, bsh, gate);
  k_xt   <<<dim3(16,4,32), 256, 0, stream>>>(x, a_s, bsh, xs_t);
  k_qkv  <<<dim3(8,6,32),  256, 0, stream>>>(wq_b, xs_t, b_qkv, qt, ktw, vv);
  k_attn <<<dim3(16,32),   256, 0, stream>>>(qt, ktw, vv, wp_b, b_proj, gate, x, out);
}

// Round 2
// 130.801 us; speedup vs baseline: 2.0838x; 2.0838x over previous
//
#include <hip/hip_runtime.h>

typedef unsigned short u16;
typedef unsigned int u32;
typedef unsigned long long u64;
typedef __attribute__((ext_vector_type(4))) float vfloat4;
typedef __attribute__((ext_vector_type(8))) short vshort8;
typedef __attribute__((ext_vector_type(4))) short vshort4;

#define DEV __device__ __forceinline__

DEV u16 f2b(float f){
  u32 u = __builtin_bit_cast(u32, f);
  u = (u + 0x7fffu + ((u >> 16) & 1u)) >> 16;
  return (u16)u;
}

typedef __attribute__((address_space(3))) u32 as3u;
typedef __attribute__((address_space(1))) u32 as1u;
DEV void gll16(const u16* g, const u16* l){
  __builtin_amdgcn_global_load_lds((const as1u*)(u64)(uintptr_t)g,
                                   (as3u*)(u32)(u64)(uintptr_t)l, 16, 0, 0);
}

// ---------------- K1: per-(b,c) sum & sumsq over N=1024 ----------------
__global__ void k_stats(const float* __restrict__ x, float* __restrict__ osum, float* __restrict__ osq){
  int row = blockIdx.x;                       // b*256 + c
  const vfloat4* xr = (const vfloat4*)(x + (size_t)row * 1024);
  vfloat4 v = xr[threadIdx.x];
  float s = v[0]+v[1]+v[2]+v[3];
  float q = v[0]*v[0]+v[1]*v[1]+v[2]*v[2]+v[3]*v[3];
  #pragma unroll
  for (int m = 1; m < 64; m <<= 1){ s += __shfl_xor(s, m); q += __shfl_xor(q, m); }
  __shared__ float ls[4], lq[4];
  int w = threadIdx.x >> 6;
  if ((threadIdx.x & 63) == 0){ ls[w] = s; lq[w] = q; }
  __syncthreads();
  if (threadIdx.x == 0){
    osum[row] = ls[0]+ls[1]+ls[2]+ls[3];
    osq[row]  = lq[0]+lq[1]+lq[2]+lq[3];
  }
}

// ---------------- K2: per-batch GN affine + SE gate ----------------
__global__ void k_prep(const float* __restrict__ sum, const float* __restrict__ sq,
                       const float* __restrict__ gamma, const float* __restrict__ beta,
                       const float* __restrict__ w_se1, const float* __restrict__ b_se1,
                       const float* __restrict__ w_se2, const float* __restrict__ b_se2,
                       float* __restrict__ a_scale, float* __restrict__ bsh, float* __restrict__ gate){
  int b = blockIdx.x, c = threadIdx.x;        // 256 threads
  __shared__ float ssh[256], qsh[256], pooled[256], h1[64], meang[32], rstdg[32];
  float s = sum[b*256 + c], q = sq[b*256 + c];
  ssh[c] = s; qsh[c] = q; pooled[c] = s * (1.f/1024.f);
  __syncthreads();
  if (c < 32){
    float gs = 0.f, gq = 0.f;
    #pragma unroll
    for (int i = 0; i < 8; i++){ gs += ssh[c*8+i]; gq += qsh[c*8+i]; }
    float mean = gs * (1.f/8192.f);
    float var  = gq * (1.f/8192.f) - mean*mean;
    meang[c] = mean; rstdg[c] = rsqrtf(var + 1e-5f);
  }
  __syncthreads();
  float rs = rstdg[c>>3], mn = meang[c>>3], g = gamma[c];
  a_scale[b*256+c] = rs*g;
  bsh[b*256+c]     = beta[c] - mn*rs*g;
  if (c < 64){
    float acc = b_se1[c];
    const float* wr = w_se1 + c*256;
    for (int i = 0; i < 256; i++) acc += pooled[i]*wr[i];
    h1[c] = fmaxf(acc, 0.f);
  }
  __syncthreads();
  float acc = b_se2[c];
  const float* wr2 = w_se2 + c*64;
  #pragma unroll
  for (int j = 0; j < 64; j++) acc += h1[j]*wr2[j];
  gate[b*256+c] = 1.f / (1.f + __expf(-acc));
}

// ---------------- K3w: weights -> bf16 ----------------
__global__ void k_wcvt(const float* __restrict__ wq, const float* __restrict__ wp,
                       u16* __restrict__ wqb, u16* __restrict__ wpb){
  int i = blockIdx.x*256 + threadIdx.x;
  if (i < 196608) wqb[i] = f2b(wq[i]);
  else            wpb[i-196608] = f2b(wp[i-196608]);
}

// ---------------- K3: xs_t[b,n,c] = bf16(a*x + bsh), transposed ----------------
__global__ void k_xt(const float* __restrict__ x, const float* __restrict__ a_s,
                     const float* __restrict__ bsh, u16* __restrict__ xs_t){
  __shared__ float t[64][65];
  int b = blockIdx.z, c0 = blockIdx.y*64, n0 = blockIdx.x*64;
  int tid = threadIdx.x;
  int rr = tid >> 4, cc = (tid & 15)*4;
  #pragma unroll
  for (int itr = 0; itr < 4; itr++){
    int r = rr + itr*16;
    int c = c0 + r;
    float a = a_s[b*256 + c], bs = bsh[b*256 + c];
    vfloat4 v = *(const vfloat4*)(x + ((size_t)(b*256 + c))*1024 + n0 + cc);
    t[r][cc]   = v[0]*a + bs;
    t[r][cc+1] = v[1]*a + bs;
    t[r][cc+2] = v[2]*a + bs;
    t[r][cc+3] = v[3]*a + bs;
  }
  __syncthreads();
  int cl = tid & 63, rg = tid >> 6;
  #pragma unroll
  for (int it2 = 0; it2 < 16; it2++){
    int nl = rg*16 + it2;
    xs_t[((size_t)b*1024 + n0 + nl)*256 + c0 + cl] = f2b(t[cl][nl]);
  }
}

// ---------------- K4: qkv GEMM; store q[b,n,c] (log2e*scale folded),
//                  K/V as pre-swizzled per-32-j-tile 16KB physical images -----
__global__ __launch_bounds__(256) void k_qkv(
    const u16* __restrict__ wq_b, const u16* __restrict__ xs_t,
    const float* __restrict__ b_qkv,
    u16* __restrict__ qt, u16* __restrict__ kph, u16* __restrict__ vph){
  __shared__ u16 Alds[128*40];
  __shared__ u16 Blds[128*40];
  int b  = blockIdx.z;
  int o0 = blockIdx.y * 128;
  int n0 = blockIdx.x * 128;
  int tid = threadIdx.x;
  int w = tid >> 6, lane = tid & 63, lo = lane & 15, hi = lane >> 4;
  int wr = w >> 1, wc = w & 1;
  vfloat4 acc[4][4];
  #pragma unroll
  for (int i = 0; i < 4; i++)
    #pragma unroll
    for (int j = 0; j < 4; j++) acc[i][j] = vfloat4{0.f,0.f,0.f,0.f};

  for (int ks = 0; ks < 8; ks++){
    int c0 = ks*32;
    __syncthreads();
    #pragma unroll
    for (int i = 0; i < 2; i++){
      int cid = tid + i*256;
      int row = cid >> 2, h4 = cid & 3;
      vshort8 a = *(const vshort8*)(wq_b + (o0+row)*256 + c0 + h4*8);
      *(vshort8*)(Alds + row*40 + h4*8) = a;
      vshort8 bl = *(const vshort8*)(xs_t + ((size_t)b*1024 + n0 + row)*256 + c0 + h4*8);
      *(vshort8*)(Blds + row*40 + h4*8) = bl;
    }
    __syncthreads();
    vshort8 af[4], bf[4];
    #pragma unroll
    for (int of = 0; of < 4; of++) af[of] = *(const vshort8*)(Alds + (wr*64+of*16+lo)*40 + hi*8);
    #pragma unroll
    for (int nf = 0; nf < 4; nf++) bf[nf] = *(const vshort8*)(Blds + (wc*64+nf*16+lo)*40 + hi*8);
    #pragma unroll
    for (int of = 0; of < 4; of++)
      #pragma unroll
      for (int nf = 0; nf < 4; nf++)
        acc[of][nf] = __builtin_amdgcn_mfma_f32_16x16x32_bf16(af[of], bf[nf], acc[of][nf], 0, 0, 0);
  }

  int kind = blockIdx.y >> 1;   // 0=q, 1=k, 2=v
  #pragma unroll
  for (int of = 0; of < 4; of++){
    int ob = o0 + wr*64 + of*16 + hi*4;
    vfloat4 bq = *(const vfloat4*)(b_qkv + ob);
    #pragma unroll
    for (int nf = 0; nf < 4; nf++){
      int n = n0 + wc*64 + nf*16 + lo;
      int tile = n >> 5, j = n & 31;
      vfloat4 val = acc[of][nf];
      #pragma unroll
      for (int r = 0; r < 4; r++) val[r] += bq[r];
      if (kind == 0){
        vshort4 p;                       // fold 1/sqrt(C) * log2(e)
        #pragma unroll
        for (int r = 0; r < 4; r++) p[r] = (short)f2b(val[r] * 0.09016844f);
        *(vshort4*)(qt + ((size_t)b*1024 + n)*256 + ob) = p;
      } else if (kind == 1){
        vshort4 p;
        #pragma unroll
        for (int r = 0; r < 4; r++) p[r] = (short)f2b(val[r]);
        int cx = (ob - 256) ^ ((j & 7) << 3);   // XOR-swizzled c within 512B row
        *(vshort4*)(kph + ((size_t)b << 18) + tile*8192 + j*256 + cx) = p;
      } else {
        int pos = ((j >> 2) & 3)*8 + ((j >> 4) << 2) + (j & 3);  // b128-frag order
        #pragma unroll
        for (int r = 0; r < 4; r++){
          int c = ob - 512 + r;
          int off = ((c >> 1) << 6) + (((((c & 1) << 5) + pos)) ^ (((c >> 1) & 7) << 3));
          vph[((size_t)b << 18) + tile*8192 + off] = f2b(val[r]);
        }
      }
    }
  }
}

// ---------------- K5: flash attention + proj + SE gate + residual ----------------
// 4 waves x 32 q-rows (f=2 fragment reuse), KVBLK=32, double-buffered
// global_load_lds staging of pre-swizzled K/V tile images.
__global__ __launch_bounds__(256, 1) void k_attn(
    const u16* __restrict__ qt, const u16* __restrict__ kph, const u16* __restrict__ vph,
    const u16* __restrict__ wp_b, const float* __restrict__ b_proj,
    const float* __restrict__ gate, const float* __restrict__ x,
    float* __restrict__ out){
  __shared__ u16 smem[33792];   // staging: K[2][8192] + V[2][8192]; overlay Ol[128][264]
  int b = blockIdx.y, i0 = blockIdx.x * 128;
  int tid = threadIdx.x, w = tid >> 6, lane = tid & 63, lo = lane & 15, hi = lane >> 4;

  // Q fragments: 2 i-frags x 8 k-steps (scale*log2e already folded in)
  vshort8 qf[2][8];
  #pragma unroll
  for (int f = 0; f < 2; f++){
    int iq = i0 + w*32 + f*16 + lo;
    #pragma unroll
    for (int ct = 0; ct < 8; ct++)
      qf[f][ct] = *(const vshort8*)(qt + ((size_t)b*1024 + iq)*256 + ct*32 + hi*8);
  }

  vfloat4 Oacc[16][2];
  #pragma unroll
  for (int i = 0; i < 16; i++){ Oacc[i][0] = vfloat4{0.f,0.f,0.f,0.f}; Oacc[i][1] = vfloat4{0.f,0.f,0.f,0.f}; }
  float m_run[2] = {-1e30f, -1e30f}, l_run[2] = {0.f, 0.f};

  // lane-constant swizzled LDS offsets
  int kswz = (lo & 7) << 3;
  int koff[8];
  #pragma unroll
  for (int ct = 0; ct < 8; ct++) koff[ct] = (ct*32 + hi*8) ^ kswz;
  int vbase = (lo >> 1)*64 + ((((lo & 1) << 5) + hi*8) ^ (((lo >> 1) & 7) << 3));

  const u16* kbat = kph + ((size_t)b << 18);
  const u16* vbat = vph + ((size_t)b << 18);

  auto STAGE = [&](int tt, int buf){
    const u16* ks = kbat + (size_t)tt * 8192;
    const u16* vs = vbat + (size_t)tt * 8192;
    u16* kd = smem + buf * 8192;
    u16* vd = smem + 16384 + buf * 8192;
    #pragma unroll
    for (int s = 0; s < 4; s++){
      int ch = (s*256 + tid) * 8;
      gll16(ks + ch, kd + ch);
      gll16(vs + ch, vd + ch);
    }
  };

  STAGE(0, 0);
  __syncthreads();

  for (int t = 0; t < 32; t++){
    int buf = t & 1;
    if (t < 31) STAGE(t + 1, buf ^ 1);
    const u16* Kb = smem + buf*8192;
    const u16* Vb = smem + 16384 + buf*8192;

    // S^T = K · Q  (D[j][i]; rows j = hi*4+e (+16 for st[1]), col i = lo)
    vfloat4 st[2][2];
    st[0][0] = vfloat4{0.f,0.f,0.f,0.f}; st[0][1] = vfloat4{0.f,0.f,0.f,0.f};
    st[1][0] = vfloat4{0.f,0.f,0.f,0.f}; st[1][1] = vfloat4{0.f,0.f,0.f,0.f};
    #pragma unroll
    for (int ct = 0; ct < 8; ct++){
      vshort8 k0 = *(const vshort8*)(Kb + lo*256 + koff[ct]);
      vshort8 k1 = *(const vshort8*)(Kb + (16 + lo)*256 + koff[ct]);
      st[0][0] = __builtin_amdgcn_mfma_f32_16x16x32_bf16(k0, qf[0][ct], st[0][0], 0,0,0);
      st[0][1] = __builtin_amdgcn_mfma_f32_16x16x32_bf16(k0, qf[1][ct], st[0][1], 0,0,0);
      st[1][0] = __builtin_amdgcn_mfma_f32_16x16x32_bf16(k1, qf[0][ct], st[1][0], 0,0,0);
      st[1][1] = __builtin_amdgcn_mfma_f32_16x16x32_bf16(k1, qf[1][ct], st[1][1], 0,0,0);
    }

    // online softmax in log2 domain, defer-max (THR=8)
    float pm[2];
    #pragma unroll
    for (int f = 0; f < 2; f++){
      float a = fmaxf(fmaxf(st[0][f][0], st[0][f][1]), fmaxf(st[0][f][2], st[0][f][3]));
      float c = fmaxf(fmaxf(st[1][f][0], st[1][f][1]), fmaxf(st[1][f][2], st[1][f][3]));
      float p = fmaxf(a, c);
      p = fmaxf(p, __shfl_xor(p, 16));
      p = fmaxf(p, __shfl_xor(p, 32));
      pm[f] = p;
    }
    bool ok = (pm[0] - m_run[0] <= 8.f) && (pm[1] - m_run[1] <= 8.f);
    if (!__all(ok)){
      #pragma unroll
      for (int f = 0; f < 2; f++){
        float mn = fmaxf(m_run[f], pm[f]);
        float corr = exp2f(m_run[f] - mn);
        #pragma unroll
        for (int i = 0; i < 16; i++) Oacc[i][f] *= corr;
        l_run[f] *= corr;
        m_run[f] = mn;
      }
    }
    vshort8 pf[2];
    #pragma unroll
    for (int f = 0; f < 2; f++){
      float p[8], ps = 0.f;
      #pragma unroll
      for (int e = 0; e < 4; e++){
        p[e]   = exp2f(st[0][f][e] - m_run[f]);
        p[4+e] = exp2f(st[1][f][e] - m_run[f]);
        ps += p[e] + p[4+e];
      }
      ps += __shfl_xor(ps, 16); ps += __shfl_xor(ps, 32);
      l_run[f] += ps;
      #pragma unroll
      for (int e2 = 0; e2 < 8; e2++) pf[f][e2] = (short)f2b(p[e2]);
    }

    // O[c][i] += V · P  (each V-frag read feeds both i-frags)
    #pragma unroll
    for (int ct2 = 0; ct2 < 16; ct2++){
      vshort8 vf = *(const vshort8*)(Vb + ct2*512 + vbase);
      Oacc[ct2][0] = __builtin_amdgcn_mfma_f32_16x16x32_bf16(vf, pf[0], Oacc[ct2][0], 0,0,0);
      Oacc[ct2][1] = __builtin_amdgcn_mfma_f32_16x16x32_bf16(vf, pf[1], Oacc[ct2][1], 0,0,0);
    }
    __syncthreads();
  }

  float inv[2] = {1.f / l_run[0], 1.f / l_run[1]};
  u16* Ol = smem;                         // [128 i][264]
  #pragma unroll
  for (int f = 0; f < 2; f++)
    #pragma unroll
    for (int ct2 = 0; ct2 < 16; ct2++){
      vshort4 p;
      #pragma unroll
      for (int r = 0; r < 4; r++) p[r] = (short)f2b(Oacc[ct2][f][r] * inv[f]);
      *(vshort4*)(Ol + (w*32 + f*16 + lo)*264 + ct2*16 + hi*4) = p;
    }
  __syncthreads();

  // proj: wave w -> o in [w*64, w*64+64), all 128 i
  vfloat4 acc2[4][8];
  #pragma unroll
  for (int i = 0; i < 4; i++)
    #pragma unroll
    for (int j = 0; j < 8; j++) acc2[i][j] = vfloat4{0.f,0.f,0.f,0.f};
  #pragma unroll
  for (int ct = 0; ct < 8; ct++){
    vshort8 wf[4], ofr[8];
    #pragma unroll
    for (int o4 = 0; o4 < 4; o4++)
      wf[o4] = *(const vshort8*)(wp_b + (w*64 + o4*16 + lo)*256 + ct*32 + hi*8);
    #pragma unroll
    for (int i4 = 0; i4 < 8; i4++)
      ofr[i4] = *(const vshort8*)(Ol + (i4*16 + lo)*264 + ct*32 + hi*8);
    #pragma unroll
    for (int o4 = 0; o4 < 4; o4++)
      #pragma unroll
      for (int i4 = 0; i4 < 8; i4++)
        acc2[o4][i4] = __builtin_amdgcn_mfma_f32_16x16x32_bf16(wf[o4], ofr[i4], acc2[o4][i4], 0,0,0);
  }

  #pragma unroll
  for (int o4 = 0; o4 < 4; o4++){
    int ob = w*64 + o4*16 + hi*4;
    vfloat4 bp = *(const vfloat4*)(b_proj + ob);
    vfloat4 gt = *(const vfloat4*)(gate + b*256 + ob);
    #pragma unroll
    for (int i4 = 0; i4 < 8; i4++){
      int n = i0 + i4*16 + lo;
      #pragma unroll
      for (int r = 0; r < 4; r++){
        size_t idx = ((size_t)(b*256) + ob + r)*1024 + n;
        out[idx] = x[idx] + (acc2[o4][i4][r] + bp[r]) * gt[r];
      }
    }
  }
}

// ---------------- launch ----------------
extern "C" void kernel_launch(void* const* d_in, const int* in_sizes, int n_in,
                              void* d_out, int out_size, void* d_ws, size_t ws_size,
                              hipStream_t stream){
  const float* x      = (const float*)d_in[0];
  const float* gamma  = (const float*)d_in[1];
  const float* beta   = (const float*)d_in[2];
  const float* w_qkv  = (const float*)d_in[3];
  const float* b_qkv  = (const float*)d_in[4];
  const float* w_proj = (const float*)d_in[5];
  const float* b_proj = (const float*)d_in[6];
  const float* w_se1  = (const float*)d_in[7];
  const float* b_se1  = (const float*)d_in[8];
  const float* w_se2  = (const float*)d_in[9];
  const float* b_se2  = (const float*)d_in[10];
  float* out = (float*)d_out;
  char* ws = (char*)d_ws;

  float* sum  = (float*)(ws + 0);          // 32 KB
  float* sq   = (float*)(ws + 32768);      // 32 KB
  float* a_s  = (float*)(ws + 65536);      // 32 KB
  float* bsh  = (float*)(ws + 98304);      // 32 KB
  float* gate = (float*)(ws + 131072);     // 32 KB
  u16* wq_b   = (u16*)(ws + 163840);       // 384 KB
  u16* wp_b   = (u16*)(ws + 557056);       // 128 KB
  u16* xs_t   = (u16*)(ws + 688128);       // 16 MB  [B,N,C] bf16
  u16* qt     = (u16*)(ws + 17465344);     // 16 MB  [B,N,C] bf16 (scale*log2e folded)
  u16* kph    = (u16*)(ws + 34242560);     // 16 MB  K tile images [B][32][8192]
  u16* vph    = (u16*)(ws + 51019776);     // 16 MB  V tile images [B][32][8192]

  k_stats<<<8192, 256, 0, stream>>>(x, sum, sq);
  k_wcvt <<<1024, 256, 0, stream>>>(w_qkv, w_proj, wq_b, wp_b);
  k_prep <<<32,   256, 0, stream>>>(sum, sq, gamma, beta, w_se1, b_se1, w_se2, b_se2, a_s, bsh, gate);
  k_xt   <<<dim3(16,4,32), 256, 0, stream>>>(x, a_s, bsh, xs_t);
  k_qkv  <<<dim3(8,6,32),  256, 0, stream>>>(wq_b, xs_t, b_qkv, qt, kph, vph);
  k_attn <<<dim3(8,32),    256, 0, stream>>>(qt, kph, vph, wp_b, b_proj, gate, x, out);
}